// Round 5
// baseline (999.247 us; speedup 1.0000x reference)
//
#include <hip/hip_runtime.h>
#include <cmath>

#define NN 50000
#define EE 800000
#define ET 850000        // EE + NN self-loops
#define PADCAP 1200128   // >= ET + 7*NN + slack(128), multiple of 256

// ---------------- CSR build ----------------
__global__ void k_zero(int* __restrict__ p, int n){
  int i = blockIdx.x*256 + threadIdx.x;
  if (i < n) p[i] = 0;
}

__global__ void k_fill(int* __restrict__ p){
  int i = blockIdx.x*256 + threadIdx.x;
  p[i] = NN;   // sentinel src (pad): hp[NN]=0-row, hl[NN]=-1e30 -> e=0
}

__global__ void k_hist(const int* __restrict__ ei, int* __restrict__ count){
  int e = blockIdx.x*256 + threadIdx.x;
  if (e >= ET) return;
  int d = (e < EE) ? ei[EE + e] : (e - EE);
  atomicAdd(&count[d], 1);
}

__global__ void k_bsum(const int* __restrict__ count, int* __restrict__ bsums){
  int i = blockIdx.x*256 + threadIdx.x;
  int v = (i < NN) ? ((count[i] + 7) & ~7) : 0;   // padded to x8
  #pragma unroll
  for (int m = 1; m < 64; m <<= 1) v += __shfl_xor(v, m);
  __shared__ int ws[4];
  if ((threadIdx.x & 63) == 0) ws[threadIdx.x >> 6] = v;
  __syncthreads();
  if (threadIdx.x == 0) bsums[blockIdx.x] = ws[0] + ws[1] + ws[2] + ws[3];
}

__global__ void k_bscan(const int* __restrict__ bsums, int* __restrict__ boffs, int nb){
  __shared__ int tmp[256];
  int t = threadIdx.x;
  int self = (t < nb) ? bsums[t] : 0;
  int v = self;
  for (int off = 1; off < 256; off <<= 1){
    tmp[t] = v; __syncthreads();
    int add = (t >= off) ? tmp[t - off] : 0;
    __syncthreads();
    v += add;
  }
  if (t < nb) boffs[t] = v - self;   // exclusive
}

__global__ void k_scan(const int* __restrict__ count, const int* __restrict__ boffs,
                       int* __restrict__ offs, int* __restrict__ cursor){
  __shared__ int tmp[256];
  int t = threadIdx.x;
  int gid = blockIdx.x*256 + t;
  int self = (gid < NN) ? ((count[gid] + 7) & ~7) : 0;   // padded to x8
  int v = self;
  for (int off = 1; off < 256; off <<= 1){
    tmp[t] = v; __syncthreads();
    int add = (t >= off) ? tmp[t - off] : 0;
    __syncthreads();
    v += add;
  }
  int excl = v - self + boffs[blockIdx.x];
  if (gid < NN){ offs[gid] = excl; cursor[gid] = excl; }
  if (gid == NN-1) offs[NN] = excl + self;
}

__global__ void k_scatter(const int* __restrict__ ei, int* __restrict__ cursor,
                          int* __restrict__ srcCSR){
  int e = blockIdx.x*256 + threadIdx.x;
  if (e >= ET) return;
  int s, d;
  if (e < EE){ s = ei[e]; d = ei[EE + e]; } else { s = d = e - EE; }
  int pos = atomicAdd(&cursor[d], 1);
  srcCSR[pos] = s;
}

// ---------------- compute ----------------
// h0 = x@W0 + b0 ; hp0 = h0@Ws[0] ; hl0 = hp0.att_l[0] ; hr0 = hp0.att_r[0]
__global__ __launch_bounds__(256) void k_prologue(
    const float* __restrict__ x, const float* __restrict__ W0, const float* __restrict__ b0,
    const float* __restrict__ Ws0, const float* __restrict__ al0, const float* __restrict__ ar0,
    float* __restrict__ hp_out, float* __restrict__ hl_out, float* __restrict__ hr_out){
  __shared__ float w0[128*32];
  __shared__ float w1[32*32];
  int t = threadIdx.x;
  for (int i = t; i < 4096; i += 256) w0[i] = W0[i];
  for (int i = t; i < 1024; i += 256) w1[i] = Ws0[i];
  __syncthreads();
  int g = t >> 5, lane = t & 31;
  int n = blockIdx.x*8 + g;                 // 6250*8 == 50000, no bounds check
  const float4* x4 = (const float4*)(x + (size_t)n*128);
  float h = b0[lane];
  #pragma unroll
  for (int j4 = 0; j4 < 32; ++j4){
    float4 xv = x4[j4];
    h += xv.x * w0[(j4*4+0)*32 + lane];
    h += xv.y * w0[(j4*4+1)*32 + lane];
    h += xv.z * w0[(j4*4+2)*32 + lane];
    h += xv.w * w0[(j4*4+3)*32 + lane];
  }
  float hp = 0.f;
  #pragma unroll
  for (int j = 0; j < 32; ++j) hp += __shfl(h, j, 32) * w1[j*32 + lane];
  float tl = hp*al0[lane], tr = hp*ar0[lane];
  #pragma unroll
  for (int m = 1; m < 32; m <<= 1){ tl += __shfl_xor(tl, m); tr += __shfl_xor(tr, m); }
  hp_out[(size_t)n*32 + lane] = hp;
  if (lane == 0){ hl_out[n] = tl; hr_out[n] = tr; }
  if (blockIdx.x == 0){
    if (g == 0) hp_out[(size_t)NN*32 + lane] = 0.f;   // pad row
    if (t == 0) hl_out[NN] = -1e30f;                  // pad sentinel -> e=0
  }
}

// One SuperGAT layer. One wave64 per dst node: octet (8 lanes) = 1 edge,
// lane holds float4 of features. 8 edges per gather instruction. Software
// pipeline: iter i issues iter i+1's row/hl gathers and iter i+2's indices,
// then computes iter i. CSR padded to x8; over-end prefetch reads neighbor
// segments / sentinel slack (always in-bounds).
__global__ __launch_bounds__(256) void k_layer(
    const float* __restrict__ hp, const float* __restrict__ hl, const float* __restrict__ hr,
    const int* __restrict__ offs, const int* __restrict__ srcCSR,
    const float* __restrict__ bcur,
    const float* __restrict__ Wn, const float* __restrict__ aln, const float* __restrict__ arn,
    const float* __restrict__ b16,
    float* __restrict__ hp_out, float* __restrict__ hl_out, float* __restrict__ hr_out,
    float* __restrict__ final_out, int last){
  __shared__ float wl[1024];
  __shared__ float xbuf[4*32];
  int t = threadIdx.x;
  int nW = last ? 512 : 1024;
  for (int i = t; i < nW; i += 256) wl[i] = Wn[i];
  __syncthreads();
  int wave = t >> 6, lane = t & 63;
  int oct = lane >> 3, li = lane & 7;
  int d = blockIdx.x*4 + wave;              // 12500*4 == 50000
  float4 hpd4 = *((const float4*)(hp + (size_t)d*32) + li);
  float hrd = hr[d];
  int beg = offs[d], end = offs[d+1];       // multiple of 8, uniform per wave

  // pipeline prologue: iter0 rows + iter1 indices
  int sA = srcCSR[beg + oct];
  float4 vA = *((const float4*)(hp + ((size_t)sA << 5)) + li);
  float hlA = hl[sA];
  int sB = srcCSR[beg + 8 + oct];

  float4 acc = {0.f,0.f,0.f,0.f};
  float den = 0.f;
  for (int i = beg; i < end; i += 8){
    // prefetch next iter's rows + the following iter's indices
    float4 vB = *((const float4*)(hp + ((size_t)sB << 5)) + li);
    float hlB = hl[sB];
    int sC = srcCSR[i + 16 + oct];
    // compute current iter (vA/hlA landed during previous iter)
    float p = vA.x*hpd4.x + vA.y*hpd4.y + vA.z*hpd4.z + vA.w*hpd4.w;
    p += __shfl_xor(p, 1); p += __shfl_xor(p, 2); p += __shfl_xor(p, 4);
    float a = (hlA + hrd) * (1.f/(1.f + __expf(-p)));
    a = fmaxf(a, 0.2f*a);
    float e = __expf(a);
    den += e;
    acc.x += vA.x*e; acc.y += vA.y*e; acc.z += vA.z*e; acc.w += vA.w*e;
    vA = vB; hlA = hlB; sB = sC;
  }
  // cross-octet reduce: within-octet lanes identical for den; acc per-feature
  #pragma unroll
  for (int m = 8; m <= 32; m <<= 1){
    acc.x += __shfl_xor(acc.x, m);
    acc.y += __shfl_xor(acc.y, m);
    acc.z += __shfl_xor(acc.z, m);
    acc.w += __shfl_xor(acc.w, m);
    den   += __shfl_xor(den, m);
  }
  float rdent = 1.f/den;
  float4 b4 = *((const float4*)bcur + li);
  float4 hnew4;
  hnew4.x = fmaxf(acc.x*rdent + b4.x, 0.f);
  hnew4.y = fmaxf(acc.y*rdent + b4.y, 0.f);
  hnew4.z = fmaxf(acc.z*rdent + b4.z, 0.f);
  hnew4.w = fmaxf(acc.w*rdent + b4.w, 0.f);
  if (oct == 0) *((float4*)(xbuf + wave*32) + li) = hnew4;
  // same-wave LDS write->read: compiler inserts lgkmcnt wait, no barrier needed
  const float* xb = xbuf + wave*32;
  int l31 = lane & 31;

  if (!last){
    float hpn = 0.f;
    #pragma unroll
    for (int j = 0; j < 32; j += 4){
      float4 hv = *(const float4*)(xb + j);
      hpn += hv.x*wl[(j+0)*32 + l31];
      hpn += hv.y*wl[(j+1)*32 + l31];
      hpn += hv.z*wl[(j+2)*32 + l31];
      hpn += hv.w*wl[(j+3)*32 + l31];
    }
    float tl = hpn*aln[l31], tr = hpn*arn[l31];
    #pragma unroll
    for (int m = 1; m < 32; m <<= 1){ tl += __shfl_xor(tl, m); tr += __shfl_xor(tr, m); }
    if (lane < 32) hp_out[(size_t)d*32 + lane] = hpn;
    if (lane == 0){ hl_out[d] = tl; hr_out[d] = tr; }
    if (blockIdx.x == 0){
      if (t < 32) hp_out[(size_t)NN*32 + t] = 0.f;
      if (t == 0) hl_out[NN] = -1e30f;
    }
  } else {
    int k = lane & 15;
    float o = b16[k];
    #pragma unroll
    for (int j = 0; j < 32; j += 4){
      float4 hv = *(const float4*)(xb + j);
      o += hv.x*wl[(j+0)*16 + k];
      o += hv.y*wl[(j+1)*16 + k];
      o += hv.z*wl[(j+2)*16 + k];
      o += hv.w*wl[(j+3)*16 + k];
    }
    if (lane < 16) final_out[(size_t)d*16 + lane] = o;
  }
}

extern "C" void kernel_launch(void* const* d_in, const int* in_sizes, int n_in,
                              void* d_out, int out_size, void* d_ws, size_t ws_size,
                              hipStream_t stream){
  const float* x   = (const float*)d_in[0];
  const int*   ei  = (const int*)  d_in[1];
  const float* W0  = (const float*)d_in[2];
  const float* b0  = (const float*)d_in[3];
  const float* Ws  = (const float*)d_in[4];
  const float* al  = (const float*)d_in[5];
  const float* ar  = (const float*)d_in[6];
  const float* bs  = (const float*)d_in[7];
  const float* W16 = (const float*)d_in[8];
  const float* b16 = (const float*)d_in[9];
  float* out = (float*)d_out;

  char* w = (char*)d_ws;
  int* count   = (int*)w;   w += 50176*sizeof(int);
  int* offs    = (int*)w;   w += 50176*sizeof(int);
  int* cursor  = (int*)w;   w += 50176*sizeof(int);
  int* srcCSR  = (int*)w;   w += (size_t)PADCAP*sizeof(int);
  int* bsums   = (int*)w;   w += 256*sizeof(int);
  int* boffs   = (int*)w;   w += 256*sizeof(int);
  float* hpA   = (float*)w; w += (size_t)(NN+1)*32*sizeof(float);
  float* hpB   = (float*)w; w += (size_t)(NN+1)*32*sizeof(float);
  float* hlA   = (float*)w; w += 50176*sizeof(float);
  float* hrA   = (float*)w; w += 50176*sizeof(float);
  float* hlB   = (float*)w; w += 50176*sizeof(float);
  float* hrB   = (float*)w; w += 50176*sizeof(float);
  // total ~22.3 MB of d_ws

  // CSR build (rebuilt every call; ws is re-poisoned by the harness)
  k_zero   <<<196, 256, 0, stream>>>(count, NN);
  k_fill   <<<PADCAP/256, 256, 0, stream>>>(srcCSR);
  k_hist   <<<3321,256, 0, stream>>>(ei, count);
  k_bsum   <<<196, 256, 0, stream>>>(count, bsums);
  k_bscan  <<<1,   256, 0, stream>>>(bsums, boffs, 196);
  k_scan   <<<196, 256, 0, stream>>>(count, boffs, offs, cursor);
  k_scatter<<<3321,256, 0, stream>>>(ei, cursor, srcCSR);

  // h0 = x@W0+b0 fused with layer-0 transform
  k_prologue<<<6250, 256, 0, stream>>>(x, W0, b0, Ws, al, ar, hpA, hlA, hrA);

  for (int l = 0; l < 15; ++l){
    const float* hin  = (l & 1) ? hpB : hpA;
    const float* hlin = (l & 1) ? hlB : hlA;
    const float* hrin = (l & 1) ? hrB : hrA;
    float* hout  = (l & 1) ? hpA : hpB;
    float* hlout = (l & 1) ? hlA : hlB;
    float* hrout = (l & 1) ? hrA : hrB;
    int last = (l == 14);
    const float* Wn  = last ? W16 : (Ws + (size_t)(l+1)*1024);
    const float* aln = last ? al  : (al + (size_t)(l+1)*32);
    const float* arn = last ? ar  : (ar + (size_t)(l+1)*32);
    k_layer<<<12500, 256, 0, stream>>>(hin, hlin, hrin, offs, srcCSR,
                                       bs + (size_t)l*32,
                                       Wn, aln, arn, b16,
                                       hout, hlout, hrout, out, last);
  }
}

// Round 6
// 938.405 us; speedup vs baseline: 1.0648x; 1.0648x over previous
//
#include <hip/hip_runtime.h>
#include <cmath>

#define NN 50000
#define EE 800000
#define ET 850000        // EE + NN self-loops
#define DB 512           // degree-sort bins

// ---------------- CSR build ----------------
__global__ void k_zero(int* __restrict__ p, int n){
  int i = blockIdx.x*256 + threadIdx.x;
  if (i < n) p[i] = 0;
}

__global__ void k_hist(const int* __restrict__ ei, int* __restrict__ count){
  int e = blockIdx.x*256 + threadIdx.x;
  if (e >= ET) return;
  int d = (e < EE) ? ei[EE + e] : (e - EE);
  atomicAdd(&count[d], 1);
}

__global__ void k_bsum(const int* __restrict__ count, int* __restrict__ bsums){
  int i = blockIdx.x*256 + threadIdx.x;
  int v = (i < NN) ? count[i] : 0;
  #pragma unroll
  for (int m = 1; m < 64; m <<= 1) v += __shfl_xor(v, m);
  __shared__ int ws[4];
  if ((threadIdx.x & 63) == 0) ws[threadIdx.x >> 6] = v;
  __syncthreads();
  if (threadIdx.x == 0) bsums[blockIdx.x] = ws[0] + ws[1] + ws[2] + ws[3];
}

__global__ void k_bscan(const int* __restrict__ bsums, int* __restrict__ boffs, int nb){
  __shared__ int tmp[256];
  int t = threadIdx.x;
  int self = (t < nb) ? bsums[t] : 0;
  int v = self;
  for (int off = 1; off < 256; off <<= 1){
    tmp[t] = v; __syncthreads();
    int add = (t >= off) ? tmp[t - off] : 0;
    __syncthreads();
    v += add;
  }
  if (t < nb) boffs[t] = v - self;   // exclusive
}

__global__ void k_scan(const int* __restrict__ count, const int* __restrict__ boffs,
                       int* __restrict__ offs, int* __restrict__ cursor){
  __shared__ int tmp[256];
  int t = threadIdx.x;
  int gid = blockIdx.x*256 + t;
  int self = (gid < NN) ? count[gid] : 0;
  int v = self;
  for (int off = 1; off < 256; off <<= 1){
    tmp[t] = v; __syncthreads();
    int add = (t >= off) ? tmp[t - off] : 0;
    __syncthreads();
    v += add;
  }
  int excl = v - self + boffs[blockIdx.x];
  if (gid < NN){ offs[gid] = excl; cursor[gid] = excl; }
  if (gid == NN-1) offs[NN] = excl + self;   // == ET
}

__global__ void k_scatter(const int* __restrict__ ei, int* __restrict__ cursor,
                          int* __restrict__ srcCSR){
  int e = blockIdx.x*256 + threadIdx.x;
  if (e >= ET) return;
  int s, d;
  if (e < EE){ s = ei[e]; d = ei[EE + e]; } else { s = d = e - EE; }
  int pos = atomicAdd(&cursor[d], 1);
  srcCSR[pos] = s;
}

// ---------------- degree sort (descending) ----------------
__global__ void k_permfill(int* __restrict__ perm){
  int i = blockIdx.x*256 + threadIdx.x;
  perm[i] = NN;   // dummy dst (len 0); grid covers 50176
}

__global__ void k_dhist(const int* __restrict__ count, int* __restrict__ dhist){
  int i = blockIdx.x*256 + threadIdx.x;
  if (i >= NN) return;
  int deg = count[i]; if (deg > DB-1) deg = DB-1;
  atomicAdd(&dhist[DB-1-deg], 1);
}

__global__ void k_dscan(const int* __restrict__ dhist, int* __restrict__ dcur){
  __shared__ int tmp[DB];
  int t = threadIdx.x;
  int self = dhist[t];
  int v = self;
  for (int off = 1; off < DB; off <<= 1){
    tmp[t] = v; __syncthreads();
    int add = (t >= off) ? tmp[t - off] : 0;
    __syncthreads();
    v += add;
  }
  dcur[t] = v - self;   // exclusive
}

__global__ void k_dscatter(const int* __restrict__ count, int* __restrict__ dcur,
                           int* __restrict__ perm){
  int i = blockIdx.x*256 + threadIdx.x;
  if (i >= NN) return;
  int deg = count[i]; if (deg > DB-1) deg = DB-1;
  int pos = atomicAdd(&dcur[DB-1-deg], 1);
  perm[pos] = i;
}

// ---------------- compute ----------------
// h0 = x@W0 + b0 ; hp0 = h0@Ws[0] ; hl0 = hp0.att_l[0] ; hr0 = hp0.att_r[0]
__global__ __launch_bounds__(256) void k_prologue(
    const float* __restrict__ x, const float* __restrict__ W0, const float* __restrict__ b0,
    const float* __restrict__ Ws0, const float* __restrict__ al0, const float* __restrict__ ar0,
    float* __restrict__ hp_out, float* __restrict__ hl_out, float* __restrict__ hr_out){
  __shared__ __align__(16) float w0[128*32];
  __shared__ __align__(16) float w1[32*32];
  int t = threadIdx.x;
  for (int i = t; i < 4096; i += 256) w0[i] = W0[i];
  for (int i = t; i < 1024; i += 256) w1[i] = Ws0[i];
  __syncthreads();
  int g = t >> 5, lane = t & 31;
  int n = blockIdx.x*8 + g;                 // 6250*8 == 50000
  const float4* x4 = (const float4*)(x + (size_t)n*128);
  float h = b0[lane];
  #pragma unroll
  for (int j4 = 0; j4 < 32; ++j4){
    float4 xv = x4[j4];
    h += xv.x * w0[(j4*4+0)*32 + lane];
    h += xv.y * w0[(j4*4+1)*32 + lane];
    h += xv.z * w0[(j4*4+2)*32 + lane];
    h += xv.w * w0[(j4*4+3)*32 + lane];
  }
  float hp = 0.f;
  #pragma unroll
  for (int j = 0; j < 32; ++j) hp += __shfl(h, j, 32) * w1[j*32 + lane];
  float tl = hp*al0[lane], tr = hp*ar0[lane];
  #pragma unroll
  for (int m = 1; m < 32; m <<= 1){ tl += __shfl_xor(tl, m); tr += __shfl_xor(tr, m); }
  hp_out[(size_t)n*32 + lane] = hp;
  if (lane == 0){ hl_out[n] = tl; hr_out[n] = tr; }
  if (blockIdx.x == 0){
    if (g == 0) hp_out[(size_t)NN*32 + lane] = 0.f;   // pad row (zeros)
    if (t == 0) hl_out[NN] = -1e30f;                  // sentinel -> e=0
  }
}

// One SuperGAT layer. Octet (8 lanes) = one dst node, 8 dst per wave, 32 per
// block. Per iter the wave processes 8 edges with 3 VMEM instrs. Each lane's
// acc float4 is the complete result for its 4 features; den is complete on
// every lane (redundant within octet) -> NO epilogue reduction. Degree-sorted
// perm gives near-uniform lens within a wave. Depth-1 row prefetch.
__global__ __launch_bounds__(256) void k_layer(
    const float* __restrict__ hp, const float* __restrict__ hl, const float* __restrict__ hr,
    const int* __restrict__ offs, const int* __restrict__ srcCSR, const int* __restrict__ perm,
    const float* __restrict__ bcur,
    const float* __restrict__ Wn, const float* __restrict__ aln, const float* __restrict__ arn,
    const float* __restrict__ b16,
    float* __restrict__ hp_out, float* __restrict__ hl_out, float* __restrict__ hr_out,
    float* __restrict__ final_out, int last){
  __shared__ __align__(16) float wl[1024];
  __shared__ __align__(16) float xb[32*36];   // stride 36: kills 8-way bank conflict
  int t = threadIdx.x;
  int nW = last ? 512 : 1024;
  for (int i = t; i < nW; i += 256) wl[i] = Wn[i];
  __syncthreads();
  int lane = t & 63;
  int li = lane & 7;                // feature quad within octet
  int slot = t >> 3;                // 0..31 dst slot within block
  int d = perm[blockIdx.x*32 + slot];
  int beg = offs[d];
  int len = offs[d+1] - beg;        // 0 for dummy d==NN (offs[NN]==offs[NN+..]? beg=ET,len via offs[NN+1]?)
  // careful: for d==NN, offs[d+1] is out of the scanned range; offs alloc has
  // slack and offs[NN]==ET; define len safely:
  len = (d < NN) ? len : 0;
  float4 hpd4 = *((const float4*)(hp + (size_t)d*32) + li);
  float hrd = hr[d];
  int cl = (len > 0) ? len - 1 : 0;

  // wave-uniform max length (degree sort makes spread tiny)
  int maxlen = len;
  #pragma unroll
  for (int m = 1; m < 64; m <<= 1) maxlen = max(maxlen, __shfl_xor(maxlen, m));

  // pipeline prologue (i = 0)
  int s_raw = srcCSR[beg];                   // in-bounds (slack for dummy)
  int s = (len > 0) ? s_raw : NN;
  float4 v = *((const float4*)(hp + ((size_t)s << 5)) + li);
  float hls = hl[s];

  float4 acc = {0.f,0.f,0.f,0.f};
  float den = 0.f;
  for (int i = 0; i < maxlen; ++i){
    // prefetch i+1 (clamped address, sentinel select)
    int nx = i + 1; if (nx > cl) nx = cl;
    int t2 = srcCSR[beg + nx];
    int s2 = (i + 1 < len) ? t2 : NN;
    float4 v2 = *((const float4*)(hp + ((size_t)s2 << 5)) + li);
    float hl2 = hl[s2];
    // compute current edge (one per octet)
    float p = v.x*hpd4.x + v.y*hpd4.y + v.z*hpd4.z + v.w*hpd4.w;
    p += __shfl_xor(p, 1); p += __shfl_xor(p, 2); p += __shfl_xor(p, 4);
    float a = (hls + hrd) * (1.f/(1.f + __expf(-p)));
    a = fmaxf(a, 0.2f*a);
    float e = __expf(a);
    den += e;
    acc.x += v.x*e; acc.y += v.y*e; acc.z += v.z*e; acc.w += v.w*e;
    v = v2; hls = hl2;
  }

  float rden = 1.f/den;               // dummy: 0/0 -> NaN, stores are guarded
  float4 b4 = *((const float4*)bcur + li);
  float4 h4;
  h4.x = fmaxf(acc.x*rden + b4.x, 0.f);
  h4.y = fmaxf(acc.y*rden + b4.y, 0.f);
  h4.z = fmaxf(acc.z*rden + b4.z, 0.f);
  h4.w = fmaxf(acc.w*rden + b4.w, 0.f);
  float* hrow = xb + slot*36;
  *((float4*)hrow + li) = h4;         // same-wave LDS write->read (lgkmcnt)

  if (!last){
    // o[j] = sum_k h[k] * Wn[k][j], lane computes j in {4li..4li+3}
    float4 o = {0.f,0.f,0.f,0.f};
    #pragma unroll
    for (int q = 0; q < 8; ++q){
      float4 hq = *((const float4*)hrow + q);
      float4 w0 = *(const float4*)(wl + (4*q+0)*32 + 4*li);
      float4 w1 = *(const float4*)(wl + (4*q+1)*32 + 4*li);
      float4 w2 = *(const float4*)(wl + (4*q+2)*32 + 4*li);
      float4 w3 = *(const float4*)(wl + (4*q+3)*32 + 4*li);
      o.x += hq.x*w0.x + hq.y*w1.x + hq.z*w2.x + hq.w*w3.x;
      o.y += hq.x*w0.y + hq.y*w1.y + hq.z*w2.y + hq.w*w3.y;
      o.z += hq.x*w0.z + hq.y*w1.z + hq.z*w2.z + hq.w*w3.z;
      o.w += hq.x*w0.w + hq.y*w1.w + hq.z*w2.w + hq.w*w3.w;
    }
    float4 a4 = *((const float4*)aln + li);
    float4 r4 = *((const float4*)arn + li);
    float tl = o.x*a4.x + o.y*a4.y + o.z*a4.z + o.w*a4.w;
    float tr = o.x*r4.x + o.y*r4.y + o.z*r4.z + o.w*r4.w;
    tl += __shfl_xor(tl, 1); tl += __shfl_xor(tl, 2); tl += __shfl_xor(tl, 4);
    tr += __shfl_xor(tr, 1); tr += __shfl_xor(tr, 2); tr += __shfl_xor(tr, 4);
    if (d < NN){
      *((float4*)(hp_out + (size_t)d*32) + li) = o;
      if (li == 0){ hl_out[d] = tl; hr_out[d] = tr; }
    }
    if (blockIdx.x == 0){
      if (t < 32) hp_out[(size_t)NN*32 + t] = 0.f;
      if (t == 0) hl_out[NN] = -1e30f;
    }
  } else {
    // out[j] = b16[j] + sum_k h[k] * W16[k][j], lane computes j in {2li,2li+1}
    const float2* b2 = (const float2*)b16;
    float2 o = b2[li];
    #pragma unroll
    for (int q = 0; q < 8; ++q){
      float4 hq = *((const float4*)hrow + q);
      float2 w0 = *(const float2*)(wl + (4*q+0)*16 + 2*li);
      float2 w1 = *(const float2*)(wl + (4*q+1)*16 + 2*li);
      float2 w2 = *(const float2*)(wl + (4*q+2)*16 + 2*li);
      float2 w3 = *(const float2*)(wl + (4*q+3)*16 + 2*li);
      o.x += hq.x*w0.x + hq.y*w1.x + hq.z*w2.x + hq.w*w3.x;
      o.y += hq.x*w0.y + hq.y*w1.y + hq.z*w2.y + hq.w*w3.y;
    }
    if (d < NN) *((float2*)(final_out + (size_t)d*16) + li) = o;
  }
}

extern "C" void kernel_launch(void* const* d_in, const int* in_sizes, int n_in,
                              void* d_out, int out_size, void* d_ws, size_t ws_size,
                              hipStream_t stream){
  const float* x   = (const float*)d_in[0];
  const int*   ei  = (const int*)  d_in[1];
  const float* W0  = (const float*)d_in[2];
  const float* b0  = (const float*)d_in[3];
  const float* Ws  = (const float*)d_in[4];
  const float* al  = (const float*)d_in[5];
  const float* ar  = (const float*)d_in[6];
  const float* bs  = (const float*)d_in[7];
  const float* W16 = (const float*)d_in[8];
  const float* b16 = (const float*)d_in[9];
  float* out = (float*)d_out;

  char* w = (char*)d_ws;
  int* count   = (int*)w;   w += 50176*sizeof(int);
  int* offs    = (int*)w;   w += 50432*sizeof(int);   // offs[NN]=ET + slack
  int* cursor  = (int*)w;   w += 50176*sizeof(int);
  int* srcCSR  = (int*)w;   w += 850432*sizeof(int);  // ET + slack
  int* bsums   = (int*)w;   w += 256*sizeof(int);
  int* boffs   = (int*)w;   w += 256*sizeof(int);
  int* perm    = (int*)w;   w += 50176*sizeof(int);
  int* dhist   = (int*)w;   w += DB*sizeof(int);
  int* dcur    = (int*)w;   w += DB*sizeof(int);
  float* hpA   = (float*)w; w += (size_t)(NN+1)*32*sizeof(float);
  float* hpB   = (float*)w; w += (size_t)(NN+1)*32*sizeof(float);
  float* hlA   = (float*)w; w += 50176*sizeof(float);
  float* hrA   = (float*)w; w += 50176*sizeof(float);
  float* hlB   = (float*)w; w += 50176*sizeof(float);
  float* hrB   = (float*)w; w += 50176*sizeof(float);
  // ~17.5 MB of d_ws

  // CSR build
  k_zero   <<<196, 256, 0, stream>>>(count, NN);
  k_zero   <<<2,   256, 0, stream>>>(dhist, DB);
  k_zero   <<<198, 256, 0, stream>>>(offs, 50432);   // incl. slack beyond offs[NN]
  k_permfill<<<196,256, 0, stream>>>(perm);
  k_hist   <<<3321,256, 0, stream>>>(ei, count);
  k_bsum   <<<196, 256, 0, stream>>>(count, bsums);
  k_bscan  <<<1,   256, 0, stream>>>(bsums, boffs, 196);
  k_scan   <<<196, 256, 0, stream>>>(count, boffs, offs, cursor);
  k_scatter<<<3321,256, 0, stream>>>(ei, cursor, srcCSR);
  // degree sort (descending)
  k_dhist   <<<196, 256, 0, stream>>>(count, dhist);
  k_dscan   <<<1,   DB,  0, stream>>>(dhist, dcur);
  k_dscatter<<<196, 256, 0, stream>>>(count, dcur, perm);

  // h0 = x@W0+b0 fused with layer-0 transform
  k_prologue<<<6250, 256, 0, stream>>>(x, W0, b0, Ws, al, ar, hpA, hlA, hrA);

  int nblk = (NN + 31) / 32 + 1;   // 1563 blocks x 32 dst = 50016 slots
  for (int l = 0; l < 15; ++l){
    const float* hin  = (l & 1) ? hpB : hpA;
    const float* hlin = (l & 1) ? hlB : hlA;
    const float* hrin = (l & 1) ? hrB : hrA;
    float* hout  = (l & 1) ? hpA : hpB;
    float* hlout = (l & 1) ? hlA : hlB;
    float* hrout = (l & 1) ? hrA : hrB;
    int last = (l == 14);
    const float* Wn  = last ? W16 : (Ws + (size_t)(l+1)*1024);
    const float* aln = last ? al  : (al + (size_t)(l+1)*32);
    const float* arn = last ? ar  : (ar + (size_t)(l+1)*32);
    k_layer<<<nblk, 256, 0, stream>>>(hin, hlin, hrin, offs, srcCSR, perm,
                                      bs + (size_t)l*32,
                                      Wn, aln, arn, b16,
                                      hout, hlout, hrout, out, last);
  }
}

// Round 7
// 665.214 us; speedup vs baseline: 1.5021x; 1.4107x over previous
//
#include <hip/hip_runtime.h>
#include <cmath>

#define NN 50000
#define EE 800000
#define ET 850000        // EE + NN self-loops
#define DB 512           // degree-sort bins
#define NB 50            // degree-sort blocks (50 x 1024 >= NN)

// ---------------- CSR build ----------------
__global__ void k_zero(int* __restrict__ p, int n){
  int i = blockIdx.x*256 + threadIdx.x;
  if (i < n) p[i] = 0;
}

__global__ void k_hist(const int* __restrict__ ei, int* __restrict__ count){
  int e = blockIdx.x*256 + threadIdx.x;
  if (e >= ET) return;
  int d = (e < EE) ? ei[EE + e] : (e - EE);
  atomicAdd(&count[d], 1);
}

__global__ void k_bsum(const int* __restrict__ count, int* __restrict__ bsums){
  int i = blockIdx.x*256 + threadIdx.x;
  int v = (i < NN) ? count[i] : 0;
  #pragma unroll
  for (int m = 1; m < 64; m <<= 1) v += __shfl_xor(v, m);
  __shared__ int ws[4];
  if ((threadIdx.x & 63) == 0) ws[threadIdx.x >> 6] = v;
  __syncthreads();
  if (threadIdx.x == 0) bsums[blockIdx.x] = ws[0] + ws[1] + ws[2] + ws[3];
}

__global__ void k_bscan(const int* __restrict__ bsums, int* __restrict__ boffs, int nb){
  __shared__ int tmp[256];
  int t = threadIdx.x;
  int self = (t < nb) ? bsums[t] : 0;
  int v = self;
  for (int off = 1; off < 256; off <<= 1){
    tmp[t] = v; __syncthreads();
    int add = (t >= off) ? tmp[t - off] : 0;
    __syncthreads();
    v += add;
  }
  if (t < nb) boffs[t] = v - self;   // exclusive
}

__global__ void k_scan(const int* __restrict__ count, const int* __restrict__ boffs,
                       int* __restrict__ offs, int* __restrict__ cursor){
  __shared__ int tmp[256];
  int t = threadIdx.x;
  int gid = blockIdx.x*256 + t;
  int self = (gid < NN) ? count[gid] : 0;
  int v = self;
  for (int off = 1; off < 256; off <<= 1){
    tmp[t] = v; __syncthreads();
    int add = (t >= off) ? tmp[t - off] : 0;
    __syncthreads();
    v += add;
  }
  int excl = v - self + boffs[blockIdx.x];
  if (gid < NN){ offs[gid] = excl; cursor[gid] = excl; }
  if (gid == NN-1) offs[NN] = excl + self;   // == ET
}

__global__ void k_scatter(const int* __restrict__ ei, int* __restrict__ cursor,
                          int* __restrict__ srcCSR){
  int e = blockIdx.x*256 + threadIdx.x;
  if (e >= ET) return;
  int s, d;
  if (e < EE){ s = ei[e]; d = ei[EE + e]; } else { s = d = e - EE; }
  int pos = atomicAdd(&cursor[d], 1);
  srcCSR[pos] = s;
}

// ---------------- degree sort (descending), block-local counting sort ----------------
__global__ void k_permfill(int* __restrict__ perm){
  int i = blockIdx.x*256 + threadIdx.x;
  perm[i] = NN;   // dummy dst (len 0); grid covers 50176
}

// per-block histogram: blockhist[bin*NB + b]
__global__ __launch_bounds__(1024) void k_dhist_blk(const int* __restrict__ count,
                                                    int* __restrict__ blockhist){
  __shared__ int hist[DB];
  int t = threadIdx.x, b = blockIdx.x;
  if (t < DB) hist[t] = 0;
  __syncthreads();
  int i = b*1024 + t;
  if (i < NN){
    int deg = count[i]; if (deg > DB-1) deg = DB-1;
    atomicAdd(&hist[DB-1-deg], 1);
  }
  __syncthreads();
  if (t < DB) blockhist[t*NB + b] = hist[t];
}

// per-bin exclusive scan across blocks + global bin-base scan (one block, DB thr)
__global__ __launch_bounds__(DB) void k_dcol(const int* __restrict__ blockhist,
                                             int* __restrict__ blockoffs,
                                             int* __restrict__ dbase){
  int k = threadIdx.x;   // bin
  int run = 0;
  #pragma unroll 5
  for (int b = 0; b < NB; ++b){
    int v = blockhist[k*NB + b];
    blockoffs[k*NB + b] = run;
    run += v;
  }
  // block-wide exclusive scan of per-bin totals (Hillis-Steele, DB threads)
  __shared__ int tmp[DB];
  int v = run;
  for (int off = 1; off < DB; off <<= 1){
    tmp[k] = v; __syncthreads();
    int add = (k >= off) ? tmp[k - off] : 0;
    __syncthreads();
    v += add;
  }
  dbase[k] = v - run;   // exclusive
}

// scatter with block-local LDS ranks — zero global atomics
__global__ __launch_bounds__(1024) void k_dscatter_blk(const int* __restrict__ count,
                                                       const int* __restrict__ blockoffs,
                                                       const int* __restrict__ dbase,
                                                       int* __restrict__ perm){
  __shared__ int hist[DB];
  int t = threadIdx.x, b = blockIdx.x;
  if (t < DB) hist[t] = 0;
  __syncthreads();
  int i = b*1024 + t;
  if (i < NN){
    int deg = count[i]; if (deg > DB-1) deg = DB-1;
    int bin = DB-1-deg;
    int rank = atomicAdd(&hist[bin], 1);
    int pos = dbase[bin] + blockoffs[bin*NB + b] + rank;
    perm[pos] = i;
  }
}

// ---------------- compute ----------------
// h0 = x@W0 + b0 ; hp0 = h0@Ws[0] ; hl0 = hp0.att_l[0] ; hr0 = hp0.att_r[0]
__global__ __launch_bounds__(256) void k_prologue(
    const float* __restrict__ x, const float* __restrict__ W0, const float* __restrict__ b0,
    const float* __restrict__ Ws0, const float* __restrict__ al0, const float* __restrict__ ar0,
    float* __restrict__ hp_out, float* __restrict__ hl_out, float* __restrict__ hr_out){
  __shared__ __align__(16) float w0[128*32];
  __shared__ __align__(16) float w1[32*32];
  int t = threadIdx.x;
  for (int i = t; i < 4096; i += 256) w0[i] = W0[i];
  for (int i = t; i < 1024; i += 256) w1[i] = Ws0[i];
  __syncthreads();
  int g = t >> 5, lane = t & 31;
  int n = blockIdx.x*8 + g;                 // 6250*8 == 50000
  const float4* x4 = (const float4*)(x + (size_t)n*128);
  float h = b0[lane];
  #pragma unroll
  for (int j4 = 0; j4 < 32; ++j4){
    float4 xv = x4[j4];
    h += xv.x * w0[(j4*4+0)*32 + lane];
    h += xv.y * w0[(j4*4+1)*32 + lane];
    h += xv.z * w0[(j4*4+2)*32 + lane];
    h += xv.w * w0[(j4*4+3)*32 + lane];
  }
  float hp = 0.f;
  #pragma unroll
  for (int j = 0; j < 32; ++j) hp += __shfl(h, j, 32) * w1[j*32 + lane];
  float tl = hp*al0[lane], tr = hp*ar0[lane];
  #pragma unroll
  for (int m = 1; m < 32; m <<= 1){ tl += __shfl_xor(tl, m); tr += __shfl_xor(tr, m); }
  hp_out[(size_t)n*32 + lane] = hp;
  if (lane == 0){ hl_out[n] = tl; hr_out[n] = tr; }
  if (blockIdx.x == 0){
    if (g == 0) hp_out[(size_t)NN*32 + lane] = 0.f;   // pad row (zeros)
    if (t == 0) hl_out[NN] = -1e30f;                  // sentinel -> e=0
  }
}

// One SuperGAT layer. Octet (8 lanes) = one dst node, 8 dst per wave, 32 per
// block. Per iter the wave processes 8 edges with 3 VMEM instrs. Each lane's
// acc float4 is the complete result for its 4 features; den is complete on
// every lane (redundant within octet) -> NO epilogue reduction. Degree-sorted
// perm gives near-uniform lens within a wave. Depth-1 row prefetch.
__global__ __launch_bounds__(256) void k_layer(
    const float* __restrict__ hp, const float* __restrict__ hl, const float* __restrict__ hr,
    const int* __restrict__ offs, const int* __restrict__ srcCSR, const int* __restrict__ perm,
    const float* __restrict__ bcur,
    const float* __restrict__ Wn, const float* __restrict__ aln, const float* __restrict__ arn,
    const float* __restrict__ b16,
    float* __restrict__ hp_out, float* __restrict__ hl_out, float* __restrict__ hr_out,
    float* __restrict__ final_out, int last){
  __shared__ __align__(16) float wl[1024];
  __shared__ __align__(16) float xb[32*36];   // stride 36: kills 8-way bank conflict
  int t = threadIdx.x;
  int nW = last ? 512 : 1024;
  for (int i = t; i < nW; i += 256) wl[i] = Wn[i];
  __syncthreads();
  int lane = t & 63;
  int li = lane & 7;                // feature quad within octet
  int slot = t >> 3;                // 0..31 dst slot within block
  int d = perm[blockIdx.x*32 + slot];
  int beg = offs[d];
  int len = offs[d+1] - beg;
  len = (d < NN) ? len : 0;
  float4 hpd4 = *((const float4*)(hp + (size_t)d*32) + li);
  float hrd = hr[d];
  int cl = (len > 0) ? len - 1 : 0;

  // wave-uniform max length (degree sort makes spread tiny)
  int maxlen = len;
  #pragma unroll
  for (int m = 1; m < 64; m <<= 1) maxlen = max(maxlen, __shfl_xor(maxlen, m));

  // pipeline prologue (i = 0)
  int s_raw = srcCSR[beg];                   // in-bounds (slack for dummy)
  int s = (len > 0) ? s_raw : NN;
  float4 v = *((const float4*)(hp + ((size_t)s << 5)) + li);
  float hls = hl[s];

  float4 acc = {0.f,0.f,0.f,0.f};
  float den = 0.f;
  for (int i = 0; i < maxlen; ++i){
    // prefetch i+1 (clamped address, sentinel select)
    int nx = i + 1; if (nx > cl) nx = cl;
    int t2 = srcCSR[beg + nx];
    int s2 = (i + 1 < len) ? t2 : NN;
    float4 v2 = *((const float4*)(hp + ((size_t)s2 << 5)) + li);
    float hl2 = hl[s2];
    // compute current edge (one per octet)
    float p = v.x*hpd4.x + v.y*hpd4.y + v.z*hpd4.z + v.w*hpd4.w;
    p += __shfl_xor(p, 1); p += __shfl_xor(p, 2); p += __shfl_xor(p, 4);
    float a = (hls + hrd) * (1.f/(1.f + __expf(-p)));
    a = fmaxf(a, 0.2f*a);
    float e = __expf(a);
    den += e;
    acc.x += v.x*e; acc.y += v.y*e; acc.z += v.z*e; acc.w += v.w*e;
    v = v2; hls = hl2;
  }

  float rden = 1.f/den;               // dummy: 0/0 -> NaN, stores are guarded
  float4 b4 = *((const float4*)bcur + li);
  float4 h4;
  h4.x = fmaxf(acc.x*rden + b4.x, 0.f);
  h4.y = fmaxf(acc.y*rden + b4.y, 0.f);
  h4.z = fmaxf(acc.z*rden + b4.z, 0.f);
  h4.w = fmaxf(acc.w*rden + b4.w, 0.f);
  float* hrow = xb + slot*36;
  *((float4*)hrow + li) = h4;         // same-wave LDS write->read (lgkmcnt)

  if (!last){
    // o[j] = sum_k h[k] * Wn[k][j], lane computes j in {4li..4li+3}
    float4 o = {0.f,0.f,0.f,0.f};
    #pragma unroll
    for (int q = 0; q < 8; ++q){
      float4 hq = *((const float4*)hrow + q);
      float4 w0 = *(const float4*)(wl + (4*q+0)*32 + 4*li);
      float4 w1 = *(const float4*)(wl + (4*q+1)*32 + 4*li);
      float4 w2 = *(const float4*)(wl + (4*q+2)*32 + 4*li);
      float4 w3 = *(const float4*)(wl + (4*q+3)*32 + 4*li);
      o.x += hq.x*w0.x + hq.y*w1.x + hq.z*w2.x + hq.w*w3.x;
      o.y += hq.x*w0.y + hq.y*w1.y + hq.z*w2.y + hq.w*w3.y;
      o.z += hq.x*w0.z + hq.y*w1.z + hq.z*w2.z + hq.w*w3.z;
      o.w += hq.x*w0.w + hq.y*w1.w + hq.z*w2.w + hq.w*w3.w;
    }
    float4 a4 = *((const float4*)aln + li);
    float4 r4 = *((const float4*)arn + li);
    float tl = o.x*a4.x + o.y*a4.y + o.z*a4.z + o.w*a4.w;
    float tr = o.x*r4.x + o.y*r4.y + o.z*r4.z + o.w*r4.w;
    tl += __shfl_xor(tl, 1); tl += __shfl_xor(tl, 2); tl += __shfl_xor(tl, 4);
    tr += __shfl_xor(tr, 1); tr += __shfl_xor(tr, 2); tr += __shfl_xor(tr, 4);
    if (d < NN){
      *((float4*)(hp_out + (size_t)d*32) + li) = o;
      if (li == 0){ hl_out[d] = tl; hr_out[d] = tr; }
    }
    if (blockIdx.x == 0){
      if (t < 32) hp_out[(size_t)NN*32 + t] = 0.f;
      if (t == 0) hl_out[NN] = -1e30f;
    }
  } else {
    // out[j] = b16[j] + sum_k h[k] * W16[k][j], lane computes j in {2li,2li+1}
    const float2* b2 = (const float2*)b16;
    float2 o = b2[li];
    #pragma unroll
    for (int q = 0; q < 8; ++q){
      float4 hq = *((const float4*)hrow + q);
      float2 w0 = *(const float2*)(wl + (4*q+0)*16 + 2*li);
      float2 w1 = *(const float2*)(wl + (4*q+1)*16 + 2*li);
      float2 w2 = *(const float2*)(wl + (4*q+2)*16 + 2*li);
      float2 w3 = *(const float2*)(wl + (4*q+3)*16 + 2*li);
      o.x += hq.x*w0.x + hq.y*w1.x + hq.z*w2.x + hq.w*w3.x;
      o.y += hq.x*w0.y + hq.y*w1.y + hq.z*w2.y + hq.w*w3.y;
    }
    if (d < NN) *((float2*)(final_out + (size_t)d*16) + li) = o;
  }
}

extern "C" void kernel_launch(void* const* d_in, const int* in_sizes, int n_in,
                              void* d_out, int out_size, void* d_ws, size_t ws_size,
                              hipStream_t stream){
  const float* x   = (const float*)d_in[0];
  const int*   ei  = (const int*)  d_in[1];
  const float* W0  = (const float*)d_in[2];
  const float* b0  = (const float*)d_in[3];
  const float* Ws  = (const float*)d_in[4];
  const float* al  = (const float*)d_in[5];
  const float* ar  = (const float*)d_in[6];
  const float* bs  = (const float*)d_in[7];
  const float* W16 = (const float*)d_in[8];
  const float* b16 = (const float*)d_in[9];
  float* out = (float*)d_out;

  char* w = (char*)d_ws;
  int* count     = (int*)w;   w += 50176*sizeof(int);
  int* offs      = (int*)w;   w += 50432*sizeof(int);   // offs[NN]=ET + slack
  int* cursor    = (int*)w;   w += 50176*sizeof(int);
  int* srcCSR    = (int*)w;   w += 850432*sizeof(int);  // ET + slack
  int* bsums     = (int*)w;   w += 256*sizeof(int);
  int* boffs     = (int*)w;   w += 256*sizeof(int);
  int* perm      = (int*)w;   w += 50176*sizeof(int);
  int* blockhist = (int*)w;   w += DB*NB*sizeof(int);
  int* blockoffs = (int*)w;   w += DB*NB*sizeof(int);
  int* dbase     = (int*)w;   w += DB*sizeof(int);
  float* hpA   = (float*)w; w += (size_t)(NN+1)*32*sizeof(float);
  float* hpB   = (float*)w; w += (size_t)(NN+1)*32*sizeof(float);
  float* hlA   = (float*)w; w += 50176*sizeof(float);
  float* hrA   = (float*)w; w += 50176*sizeof(float);
  float* hlB   = (float*)w; w += 50176*sizeof(float);
  float* hrB   = (float*)w; w += 50176*sizeof(float);
  // ~17.7 MB of d_ws

  // CSR build
  k_zero   <<<196, 256, 0, stream>>>(count, NN);
  k_zero   <<<198, 256, 0, stream>>>(offs, 50432);   // incl. slack beyond offs[NN]
  k_permfill<<<196,256, 0, stream>>>(perm);
  k_hist   <<<3321,256, 0, stream>>>(ei, count);
  k_bsum   <<<196, 256, 0, stream>>>(count, bsums);
  k_bscan  <<<1,   256, 0, stream>>>(bsums, boffs, 196);
  k_scan   <<<196, 256, 0, stream>>>(count, boffs, offs, cursor);
  k_scatter<<<3321,256, 0, stream>>>(ei, cursor, srcCSR);
  // degree sort (descending) — block-local counting sort, no global atomics
  k_dhist_blk   <<<NB, 1024, 0, stream>>>(count, blockhist);
  k_dcol        <<<1,  DB,   0, stream>>>(blockhist, blockoffs, dbase);
  k_dscatter_blk<<<NB, 1024, 0, stream>>>(count, blockoffs, dbase, perm);

  // h0 = x@W0+b0 fused with layer-0 transform
  k_prologue<<<6250, 256, 0, stream>>>(x, W0, b0, Ws, al, ar, hpA, hlA, hrA);

  int nblk = (NN + 31) / 32 + 1;   // 1563 blocks x 32 dst = 50016 slots
  for (int l = 0; l < 15; ++l){
    const float* hin  = (l & 1) ? hpB : hpA;
    const float* hlin = (l & 1) ? hlB : hlA;
    const float* hrin = (l & 1) ? hrB : hrA;
    float* hout  = (l & 1) ? hpA : hpB;
    float* hlout = (l & 1) ? hlA : hlB;
    float* hrout = (l & 1) ? hrA : hrB;
    int last = (l == 14);
    const float* Wn  = last ? W16 : (Ws + (size_t)(l+1)*1024);
    const float* aln = last ? al  : (al + (size_t)(l+1)*32);
    const float* arn = last ? ar  : (ar + (size_t)(l+1)*32);
    k_layer<<<nblk, 256, 0, stream>>>(hin, hlin, hrin, offs, srcCSR, perm,
                                      bs + (size_t)l*32,
                                      Wn, aln, arn, b16,
                                      hout, hlout, hrout, out, last);
  }
}

// Round 8
// 576.023 us; speedup vs baseline: 1.7347x; 1.1548x over previous
//
#include <hip/hip_runtime.h>
#include <hip/hip_fp16.h>
#include <cmath>
#include <cstring>

#define NN 50000
#define EE 800000
#define ET 850000        // EE + NN self-loops
#define DB 512           // degree-sort bins
#define NB 50            // degree-sort blocks (50 x 1024 >= NN)

// ---------------- CSR build ----------------
__global__ void k_zero(int* __restrict__ p, int n){
  int i = blockIdx.x*256 + threadIdx.x;
  if (i < n) p[i] = 0;
}

__global__ void k_hist(const int* __restrict__ ei, int* __restrict__ count){
  int e = blockIdx.x*256 + threadIdx.x;
  if (e >= ET) return;
  int d = (e < EE) ? ei[EE + e] : (e - EE);
  atomicAdd(&count[d], 1);
}

__global__ void k_bsum(const int* __restrict__ count, int* __restrict__ bsums){
  int i = blockIdx.x*256 + threadIdx.x;
  int v = (i < NN) ? count[i] : 0;
  #pragma unroll
  for (int m = 1; m < 64; m <<= 1) v += __shfl_xor(v, m);
  __shared__ int ws[4];
  if ((threadIdx.x & 63) == 0) ws[threadIdx.x >> 6] = v;
  __syncthreads();
  if (threadIdx.x == 0) bsums[blockIdx.x] = ws[0] + ws[1] + ws[2] + ws[3];
}

__global__ void k_bscan(const int* __restrict__ bsums, int* __restrict__ boffs, int nb){
  __shared__ int tmp[256];
  int t = threadIdx.x;
  int self = (t < nb) ? bsums[t] : 0;
  int v = self;
  for (int off = 1; off < 256; off <<= 1){
    tmp[t] = v; __syncthreads();
    int add = (t >= off) ? tmp[t - off] : 0;
    __syncthreads();
    v += add;
  }
  if (t < nb) boffs[t] = v - self;   // exclusive
}

__global__ void k_scan(const int* __restrict__ count, const int* __restrict__ boffs,
                       int* __restrict__ offs, int* __restrict__ cursor){
  __shared__ int tmp[256];
  int t = threadIdx.x;
  int gid = blockIdx.x*256 + t;
  int self = (gid < NN) ? count[gid] : 0;
  int v = self;
  for (int off = 1; off < 256; off <<= 1){
    tmp[t] = v; __syncthreads();
    int add = (t >= off) ? tmp[t - off] : 0;
    __syncthreads();
    v += add;
  }
  int excl = v - self + boffs[blockIdx.x];
  if (gid < NN){ offs[gid] = excl; cursor[gid] = excl; }
  if (gid == NN-1) offs[NN] = excl + self;   // == ET
}

__global__ void k_scatter(const int* __restrict__ ei, int* __restrict__ cursor,
                          int* __restrict__ srcCSR){
  int e = blockIdx.x*256 + threadIdx.x;
  if (e >= ET) return;
  int s, d;
  if (e < EE){ s = ei[e]; d = ei[EE + e]; } else { s = d = e - EE; }
  int pos = atomicAdd(&cursor[d], 1);
  srcCSR[pos] = s;
}

// ---------------- degree sort (descending), block-local counting sort ----------------
__global__ void k_permfill(int* __restrict__ perm){
  int i = blockIdx.x*256 + threadIdx.x;
  perm[i] = NN;   // dummy dst (len 0); grid covers 50176
}

__global__ __launch_bounds__(1024) void k_dhist_blk(const int* __restrict__ count,
                                                    int* __restrict__ blockhist){
  __shared__ int hist[DB];
  int t = threadIdx.x, b = blockIdx.x;
  if (t < DB) hist[t] = 0;
  __syncthreads();
  int i = b*1024 + t;
  if (i < NN){
    int deg = count[i]; if (deg > DB-1) deg = DB-1;
    atomicAdd(&hist[DB-1-deg], 1);
  }
  __syncthreads();
  if (t < DB) blockhist[t*NB + b] = hist[t];
}

__global__ __launch_bounds__(DB) void k_dcol(const int* __restrict__ blockhist,
                                             int* __restrict__ blockoffs,
                                             int* __restrict__ dbase){
  int k = threadIdx.x;   // bin
  int run = 0;
  #pragma unroll 5
  for (int b = 0; b < NB; ++b){
    int v = blockhist[k*NB + b];
    blockoffs[k*NB + b] = run;
    run += v;
  }
  __shared__ int tmp[DB];
  int v = run;
  for (int off = 1; off < DB; off <<= 1){
    tmp[k] = v; __syncthreads();
    int add = (k >= off) ? tmp[k - off] : 0;
    __syncthreads();
    v += add;
  }
  dbase[k] = v - run;   // exclusive
}

__global__ __launch_bounds__(1024) void k_dscatter_blk(const int* __restrict__ count,
                                                       const int* __restrict__ blockoffs,
                                                       const int* __restrict__ dbase,
                                                       int* __restrict__ perm){
  __shared__ int hist[DB];
  int t = threadIdx.x, b = blockIdx.x;
  if (t < DB) hist[t] = 0;
  __syncthreads();
  int i = b*1024 + t;
  if (i < NN){
    int deg = count[i]; if (deg > DB-1) deg = DB-1;
    int bin = DB-1-deg;
    int rank = atomicAdd(&hist[bin], 1);
    int pos = dbase[bin] + blockoffs[bin*NB + b] + rank;
    perm[pos] = i;
  }
}

// ---------------- fp16 helpers ----------------
__device__ __forceinline__ float4 cvt_row(uint2 r){
  __half2 h0, h1;
  memcpy(&h0, &r.x, 4); memcpy(&h1, &r.y, 4);
  float2 f0 = __half22float2(h0), f1 = __half22float2(h1);
  return make_float4(f0.x, f0.y, f1.x, f1.y);
}
__device__ __forceinline__ unsigned pack_h2(float x, float y){
  __half2 h = __floats2half2_rn(x, y);
  unsigned u; memcpy(&u, &h, 4); return u;
}

// ---------------- compute ----------------
// h0 = x@W0 + b0 ; hp0 = h0@Ws[0] ; hl0 = hp0.att_l[0] ; hr0 = hp0.att_r[0]
__global__ __launch_bounds__(256) void k_prologue(
    const float* __restrict__ x, const float* __restrict__ W0, const float* __restrict__ b0,
    const float* __restrict__ Ws0, const float* __restrict__ al0, const float* __restrict__ ar0,
    __half* __restrict__ hp_out, float* __restrict__ hl_out, float* __restrict__ hr_out){
  __shared__ __align__(16) float w0[128*32];
  __shared__ __align__(16) float w1[32*32];
  int t = threadIdx.x;
  for (int i = t; i < 4096; i += 256) w0[i] = W0[i];
  for (int i = t; i < 1024; i += 256) w1[i] = Ws0[i];
  __syncthreads();
  int g = t >> 5, lane = t & 31;
  int n = blockIdx.x*8 + g;                 // 6250*8 == 50000
  const float4* x4 = (const float4*)(x + (size_t)n*128);
  float h = b0[lane];
  #pragma unroll
  for (int j4 = 0; j4 < 32; ++j4){
    float4 xv = x4[j4];
    h += xv.x * w0[(j4*4+0)*32 + lane];
    h += xv.y * w0[(j4*4+1)*32 + lane];
    h += xv.z * w0[(j4*4+2)*32 + lane];
    h += xv.w * w0[(j4*4+3)*32 + lane];
  }
  float hp = 0.f;
  #pragma unroll
  for (int j = 0; j < 32; ++j) hp += __shfl(h, j, 32) * w1[j*32 + lane];
  float tl = hp*al0[lane], tr = hp*ar0[lane];
  #pragma unroll
  for (int m = 1; m < 32; m <<= 1){ tl += __shfl_xor(tl, m); tr += __shfl_xor(tr, m); }
  hp_out[(size_t)n*32 + lane] = __float2half(hp);
  if (lane == 0){ hl_out[n] = tl; hr_out[n] = tr; }
  if (blockIdx.x == 0){
    if (g == 0) hp_out[(size_t)NN*32 + lane] = __float2half(0.f);  // pad row
    if (t == 0) hl_out[NN] = -1e30f;                               // sentinel -> e=0
  }
}

// One SuperGAT layer. Octet (8 lanes) = one dst, 8 dst per wave. Edges in
// groups of 4 per octet, double-buffered software pipeline: indices at depth
// 2 groups, rows/hl at depth 1 group -- the idx->row chain never serializes
// inside an iteration (R7's bug). hp rows are fp16 (3.2 MB, per-XCD L2
// resident). Tails via sentinel (clamped addr, src=NN -> e=0).
__global__ __launch_bounds__(256) void k_layer(
    const __half* __restrict__ hp, const float* __restrict__ hl, const float* __restrict__ hr,
    const int* __restrict__ offs, const int* __restrict__ srcCSR, const int* __restrict__ perm,
    const float* __restrict__ bcur,
    const float* __restrict__ Wn, const float* __restrict__ aln, const float* __restrict__ arn,
    const float* __restrict__ b16,
    __half* __restrict__ hp_out, float* __restrict__ hl_out, float* __restrict__ hr_out,
    float* __restrict__ final_out, int last){
  __shared__ __align__(16) float wl[1024];
  __shared__ __align__(16) float xb[32*36];   // stride 36: kills 8-way bank conflict
  int t = threadIdx.x;
  int nW = last ? 512 : 1024;
  for (int i = t; i < nW; i += 256) wl[i] = Wn[i];
  __syncthreads();
  int lane = t & 63;
  int li = lane & 7;                // feature quad within octet
  int slot = t >> 3;                // 0..31 dst slot within block
  int d = perm[blockIdx.x*32 + slot];
  int beg = offs[d];
  int len = offs[d+1] - beg;
  len = (d < NN) ? len : 0;
  float4 hpd4 = cvt_row(*(const uint2*)(hp + ((size_t)d << 5) + (li << 2)));
  float hrd = hr[d];
  int cl = (len > 0) ? len - 1 : 0;

  int maxlen = len;
  #pragma unroll
  for (int m = 1; m < 64; m <<= 1) maxlen = max(maxlen, __shfl_xor(maxlen, m));
  int ng = (maxlen + 3) >> 2;
  ng = (ng + 1) & ~1;               // even # of 4-edge groups

  auto SEL = [&](int k)->int{
    int kk = (k < cl) ? k : cl;     // clamped address: always in-bounds
    int ss = srcCSR[beg + kk];
    return (k < len) ? ss : NN;     // sentinel for tail slots
  };
  auto ROW = [&](int s)->uint2{
    return *(const uint2*)(hp + ((size_t)s << 5) + (li << 2));
  };
  float4 acc = {0.f,0.f,0.f,0.f};
  float den = 0.f;
  auto EDGE = [&](uint2 r, float g){
    float4 v = cvt_row(r);
    float p = v.x*hpd4.x + v.y*hpd4.y + v.z*hpd4.z + v.w*hpd4.w;
    p += __shfl_xor(p, 1); p += __shfl_xor(p, 2); p += __shfl_xor(p, 4);
    float a = (g + hrd) * (1.f/(1.f + __expf(-p)));
    a = fmaxf(a, 0.2f*a);
    float e = __expf(a);
    den += e;
    acc.x += v.x*e; acc.y += v.y*e; acc.z += v.z*e; acc.w += v.w*e;
  };

  // pipeline preamble: group0 rows+hl, group1 indices
  int iA0=SEL(0), iA1=SEL(1), iA2=SEL(2), iA3=SEL(3);
  uint2 rA0=ROW(iA0), rA1=ROW(iA1), rA2=ROW(iA2), rA3=ROW(iA3);
  float gA0=hl[iA0], gA1=hl[iA1], gA2=hl[iA2], gA3=hl[iA3];
  int iB0=SEL(4), iB1=SEL(5), iB2=SEL(6), iB3=SEL(7);

  for (int grp = 0; grp < ng; grp += 2){
    // half-body A: issue rows for grp+1 (from iB), idx for grp+2 (into iA), compute grp
    uint2 rB0=ROW(iB0), rB1=ROW(iB1), rB2=ROW(iB2), rB3=ROW(iB3);
    float gB0=hl[iB0], gB1=hl[iB1], gB2=hl[iB2], gB3=hl[iB3];
    int b2 = (grp + 2) << 2;
    iA0=SEL(b2); iA1=SEL(b2+1); iA2=SEL(b2+2); iA3=SEL(b2+3);
    EDGE(rA0,gA0); EDGE(rA1,gA1); EDGE(rA2,gA2); EDGE(rA3,gA3);
    // half-body B: issue rows for grp+2 (from iA), idx for grp+3 (into iB), compute grp+1
    rA0=ROW(iA0); rA1=ROW(iA1); rA2=ROW(iA2); rA3=ROW(iA3);
    gA0=hl[iA0]; gA1=hl[iA1]; gA2=hl[iA2]; gA3=hl[iA3];
    int b3 = (grp + 3) << 2;
    iB0=SEL(b3); iB1=SEL(b3+1); iB2=SEL(b3+2); iB3=SEL(b3+3);
    EDGE(rB0,gB0); EDGE(rB1,gB1); EDGE(rB2,gB2); EDGE(rB3,gB3);
  }

  float rden = 1.f/den;               // dummy: 0/0 -> NaN, stores are guarded
  float4 b4 = *((const float4*)bcur + li);
  float4 h4;
  h4.x = fmaxf(acc.x*rden + b4.x, 0.f);
  h4.y = fmaxf(acc.y*rden + b4.y, 0.f);
  h4.z = fmaxf(acc.z*rden + b4.z, 0.f);
  h4.w = fmaxf(acc.w*rden + b4.w, 0.f);
  float* hrow = xb + slot*36;
  *((float4*)hrow + li) = h4;         // same-wave LDS write->read (lgkmcnt)

  if (!last){
    // o[j] = sum_k h[k] * Wn[k][j], lane computes j in {4li..4li+3}
    float4 o = {0.f,0.f,0.f,0.f};
    #pragma unroll
    for (int q = 0; q < 8; ++q){
      float4 hq = *((const float4*)hrow + q);
      float4 w0 = *(const float4*)(wl + (4*q+0)*32 + 4*li);
      float4 w1 = *(const float4*)(wl + (4*q+1)*32 + 4*li);
      float4 w2 = *(const float4*)(wl + (4*q+2)*32 + 4*li);
      float4 w3 = *(const float4*)(wl + (4*q+3)*32 + 4*li);
      o.x += hq.x*w0.x + hq.y*w1.x + hq.z*w2.x + hq.w*w3.x;
      o.y += hq.x*w0.y + hq.y*w1.y + hq.z*w2.y + hq.w*w3.y;
      o.z += hq.x*w0.z + hq.y*w1.z + hq.z*w2.z + hq.w*w3.z;
      o.w += hq.x*w0.w + hq.y*w1.w + hq.z*w2.w + hq.w*w3.w;
    }
    float4 a4 = *((const float4*)aln + li);
    float4 r4 = *((const float4*)arn + li);
    float tl = o.x*a4.x + o.y*a4.y + o.z*a4.z + o.w*a4.w;
    float tr = o.x*r4.x + o.y*r4.y + o.z*r4.z + o.w*r4.w;
    tl += __shfl_xor(tl, 1); tl += __shfl_xor(tl, 2); tl += __shfl_xor(tl, 4);
    tr += __shfl_xor(tr, 1); tr += __shfl_xor(tr, 2); tr += __shfl_xor(tr, 4);
    if (d < NN){
      uint2 st; st.x = pack_h2(o.x, o.y); st.y = pack_h2(o.z, o.w);
      *(uint2*)(hp_out + ((size_t)d << 5) + (li << 2)) = st;
      if (li == 0){ hl_out[d] = tl; hr_out[d] = tr; }
    }
    if (blockIdx.x == 0){
      if (t < 32) hp_out[(size_t)NN*32 + t] = __float2half(0.f);
      if (t == 0) hl_out[NN] = -1e30f;
    }
  } else {
    // out[j] = b16[j] + sum_k h[k] * W16[k][j], lane computes j in {2li,2li+1}
    const float2* b2p = (const float2*)b16;
    float2 o = b2p[li];
    #pragma unroll
    for (int q = 0; q < 8; ++q){
      float4 hq = *((const float4*)hrow + q);
      float2 w0 = *(const float2*)(wl + (4*q+0)*16 + 2*li);
      float2 w1 = *(const float2*)(wl + (4*q+1)*16 + 2*li);
      float2 w2 = *(const float2*)(wl + (4*q+2)*16 + 2*li);
      float2 w3 = *(const float2*)(wl + (4*q+3)*16 + 2*li);
      o.x += hq.x*w0.x + hq.y*w1.x + hq.z*w2.x + hq.w*w3.x;
      o.y += hq.x*w0.y + hq.y*w1.y + hq.z*w2.y + hq.w*w3.y;
    }
    if (d < NN) *((float2*)(final_out + (size_t)d*16) + li) = o;
  }
}

extern "C" void kernel_launch(void* const* d_in, const int* in_sizes, int n_in,
                              void* d_out, int out_size, void* d_ws, size_t ws_size,
                              hipStream_t stream){
  const float* x   = (const float*)d_in[0];
  const int*   ei  = (const int*)  d_in[1];
  const float* W0  = (const float*)d_in[2];
  const float* b0  = (const float*)d_in[3];
  const float* Ws  = (const float*)d_in[4];
  const float* al  = (const float*)d_in[5];
  const float* ar  = (const float*)d_in[6];
  const float* bs  = (const float*)d_in[7];
  const float* W16 = (const float*)d_in[8];
  const float* b16 = (const float*)d_in[9];
  float* out = (float*)d_out;

  char* w = (char*)d_ws;
  int* count     = (int*)w;   w += 50176*sizeof(int);
  int* offs      = (int*)w;   w += 50432*sizeof(int);   // offs[NN]=ET + slack
  int* cursor    = (int*)w;   w += 50176*sizeof(int);
  int* srcCSR    = (int*)w;   w += 850432*sizeof(int);  // ET + slack
  int* bsums     = (int*)w;   w += 256*sizeof(int);
  int* boffs     = (int*)w;   w += 256*sizeof(int);
  int* perm      = (int*)w;   w += 50176*sizeof(int);
  int* blockhist = (int*)w;   w += DB*NB*sizeof(int);
  int* blockoffs = (int*)w;   w += DB*NB*sizeof(int);
  int* dbase     = (int*)w;   w += DB*sizeof(int);
  __half* hpA  = (__half*)w; w += (size_t)(NN+16)*32*sizeof(__half);
  __half* hpB  = (__half*)w; w += (size_t)(NN+16)*32*sizeof(__half);
  float* hlA   = (float*)w; w += 50176*sizeof(float);
  float* hrA   = (float*)w; w += 50176*sizeof(float);
  float* hlB   = (float*)w; w += 50176*sizeof(float);
  float* hrB   = (float*)w; w += 50176*sizeof(float);
  // ~12 MB of d_ws

  // CSR build
  k_zero   <<<196, 256, 0, stream>>>(count, NN);
  k_zero   <<<198, 256, 0, stream>>>(offs, 50432);   // incl. slack beyond offs[NN]
  k_permfill<<<196,256, 0, stream>>>(perm);
  k_hist   <<<3321,256, 0, stream>>>(ei, count);
  k_bsum   <<<196, 256, 0, stream>>>(count, bsums);
  k_bscan  <<<1,   256, 0, stream>>>(bsums, boffs, 196);
  k_scan   <<<196, 256, 0, stream>>>(count, boffs, offs, cursor);
  k_scatter<<<3321,256, 0, stream>>>(ei, cursor, srcCSR);
  // degree sort (descending) — block-local counting sort, no global atomics
  k_dhist_blk   <<<NB, 1024, 0, stream>>>(count, blockhist);
  k_dcol        <<<1,  DB,   0, stream>>>(blockhist, blockoffs, dbase);
  k_dscatter_blk<<<NB, 1024, 0, stream>>>(count, blockoffs, dbase, perm);

  // h0 = x@W0+b0 fused with layer-0 transform
  k_prologue<<<6250, 256, 0, stream>>>(x, W0, b0, Ws, al, ar, hpA, hlA, hrA);

  int nblk = (NN + 31) / 32 + 1;   // 1563 blocks x 32 dst = 50016 slots
  for (int l = 0; l < 15; ++l){
    const __half* hin = (l & 1) ? hpB : hpA;
    const float* hlin = (l & 1) ? hlB : hlA;
    const float* hrin = (l & 1) ? hrB : hrA;
    __half* hout = (l & 1) ? hpA : hpB;
    float* hlout = (l & 1) ? hlA : hlB;
    float* hrout = (l & 1) ? hrA : hrB;
    int last = (l == 14);
    const float* Wn  = last ? W16 : (Ws + (size_t)(l+1)*1024);
    const float* aln = last ? al  : (al + (size_t)(l+1)*32);
    const float* arn = last ? ar  : (ar + (size_t)(l+1)*32);
    k_layer<<<nblk, 256, 0, stream>>>(hin, hlin, hrin, offs, srcCSR, perm,
                                      bs + (size_t)l*32,
                                      Wn, aln, arn, b16,
                                      hout, hlout, hrout, out, last);
  }
}

// Round 9
// 496.741 us; speedup vs baseline: 2.0116x; 1.1596x over previous
//
#include <hip/hip_runtime.h>
#include <hip/hip_fp16.h>
#include <cmath>
#include <cstring>

#define NN 50000
#define EE 800000
#define ET 850000        // EE + NN self-loops
#define PADCAP 1004544   // >= padded ET (<= ET+3*NN = 1,000,192) + slack; mult of 256
#define NBK 831          // edge blocks: 831*1024 >= ET
#define EBINS 196        // dst buckets of 256 nodes (196*256 = 50176 >= NN)
#define DB 512           // degree-sort bins
#define NB 50            // degree-sort blocks

// ---------------- sentinel prefill ----------------
__global__ void k_fill(int* __restrict__ p){
  int i = blockIdx.x*256 + threadIdx.x;
  p[i] = NN;   // sentinel src: hp[NN]=0-row, hl[NN]=-1e30 -> e=0
}

__global__ void k_permfill(int* __restrict__ perm){
  int i = blockIdx.x*256 + threadIdx.x;
  perm[i] = NN;   // dummy dst (len 0); grid covers 50176
}

// ---------------- binned CSR build (no global atomics, dense writes) ----------------
// pass 1a: per-block bucket histogram
__global__ __launch_bounds__(1024) void k_ebhist(const int* __restrict__ ei,
                                                 int* __restrict__ ebh){
  __shared__ int hist[EBINS];
  int t = threadIdx.x, b = blockIdx.x;
  if (t < EBINS) hist[t] = 0;
  __syncthreads();
  int e = b*1024 + t;
  if (e < ET){
    int d = (e < EE) ? ei[EE + e] : (e - EE);
    atomicAdd(&hist[d >> 8], 1);
  }
  __syncthreads();
  if (t < EBINS) ebh[t*NBK + b] = hist[t];
}

// pass 1b: per-bucket exclusive scan over blocks (one block per bucket)
__global__ __launch_bounds__(1024) void k_escan1(const int* __restrict__ ebh,
                                                 int* __restrict__ ebhoff,
                                                 int* __restrict__ btot){
  __shared__ int tmp[1024];
  int bin = blockIdx.x, t = threadIdx.x;
  int v = (t < NBK) ? ebh[bin*NBK + t] : 0;
  int inc = v;
  for (int off = 1; off < 1024; off <<= 1){
    tmp[t] = inc; __syncthreads();
    int add = (t >= off) ? tmp[t - off] : 0;
    __syncthreads();
    inc += add;
  }
  if (t < NBK) ebhoff[bin*NBK + t] = inc - v;
  if (t == 1023) btot[bin] = inc;
}

// pass 1c: bucket-base scan
__global__ __launch_bounds__(256) void k_escan2(const int* __restrict__ btot,
                                                int* __restrict__ bbase){
  __shared__ int tmp[256];
  int t = threadIdx.x;
  int v = (t < EBINS) ? btot[t] : 0;
  int inc = v;
  for (int off = 1; off < 256; off <<= 1){
    tmp[t] = inc; __syncthreads();
    int add = (t >= off) ? tmp[t - off] : 0;
    __syncthreads();
    inc += add;
  }
  if (t < EBINS) bbase[t] = inc - v;
  if (t == 255) bbase[EBINS] = inc;   // == ET
}

// pass 1d: scatter edges into buckets (LDS ranks, dense chunked writes)
__global__ __launch_bounds__(1024) void k_ebin(const int* __restrict__ ei,
                                               const int* __restrict__ ebhoff,
                                               const int* __restrict__ bbase,
                                               int2* __restrict__ ebuf){
  __shared__ int hist[EBINS];
  int t = threadIdx.x, b = blockIdx.x;
  if (t < EBINS) hist[t] = 0;
  __syncthreads();
  int e = b*1024 + t;
  if (e < ET){
    int s, d;
    if (e < EE){ s = ei[e]; d = ei[EE + e]; } else { s = d = e - EE; }
    int bin = d >> 8;
    int rank = atomicAdd(&hist[bin], 1);
    int pos = bbase[bin] + ebhoff[bin*NBK + b] + rank;
    ebuf[pos] = make_int2(s, d);
  }
}

// pass 2a: per-bucket dst counts (replaces global-atomic k_hist)
__global__ __launch_bounds__(1024) void k_ecnt(const int2* __restrict__ ebuf,
                                               const int* __restrict__ bbase,
                                               int* __restrict__ count){
  __shared__ int cnt[256];
  int t = threadIdx.x, bin = blockIdx.x;
  if (t < 256) cnt[t] = 0;
  __syncthreads();
  int rb = bbase[bin], re = bbase[bin+1];
  for (int i = rb + t; i < re; i += 1024) atomicAdd(&cnt[ebuf[i].y - (bin << 8)], 1);
  __syncthreads();
  int idx = (bin << 8) + t;
  if (t < 256 && idx < NN) count[idx] = cnt[t];
}

// ---------------- offs scan (padded to x4 for int4 idx alignment) ----------------
__global__ void k_bsum(const int* __restrict__ count, int* __restrict__ bsums){
  int i = blockIdx.x*256 + threadIdx.x;
  int v = (i < NN) ? ((count[i] + 3) & ~3) : 0;
  #pragma unroll
  for (int m = 1; m < 64; m <<= 1) v += __shfl_xor(v, m);
  __shared__ int ws[4];
  if ((threadIdx.x & 63) == 0) ws[threadIdx.x >> 6] = v;
  __syncthreads();
  if (threadIdx.x == 0) bsums[blockIdx.x] = ws[0] + ws[1] + ws[2] + ws[3];
}

__global__ void k_bscan(const int* __restrict__ bsums, int* __restrict__ boffs, int nb){
  __shared__ int tmp[256];
  int t = threadIdx.x;
  int self = (t < nb) ? bsums[t] : 0;
  int v = self;
  for (int off = 1; off < 256; off <<= 1){
    tmp[t] = v; __syncthreads();
    int add = (t >= off) ? tmp[t - off] : 0;
    __syncthreads();
    v += add;
  }
  if (t < nb) boffs[t] = v - self;   // exclusive
}

__global__ void k_scan(const int* __restrict__ count, const int* __restrict__ boffs,
                       int* __restrict__ offs){
  __shared__ int tmp[256];
  int t = threadIdx.x;
  int gid = blockIdx.x*256 + t;
  int self = (gid < NN) ? ((count[gid] + 3) & ~3) : 0;
  int v = self;
  for (int off = 1; off < 256; off <<= 1){
    tmp[t] = v; __syncthreads();
    int add = (t >= off) ? tmp[t - off] : 0;
    __syncthreads();
    v += add;
  }
  int excl = v - self + boffs[blockIdx.x];
  if (gid < NN) offs[gid] = excl;
  if (gid == NN-1) offs[NN] = excl + self;   // padded total
}

// pass 2b: per-bucket CSR scatter (LDS cursors; output region ~17KB contiguous)
__global__ __launch_bounds__(1024) void k_escatter(const int2* __restrict__ ebuf,
                                                   const int* __restrict__ bbase,
                                                   const int* __restrict__ offs,
                                                   int* __restrict__ srcCSR){
  __shared__ int cur[256];
  int t = threadIdx.x, bin = blockIdx.x;
  if (t < 256){ int idx = (bin << 8) + t; cur[t] = (idx < NN) ? offs[idx] : 0; }
  __syncthreads();
  int rb = bbase[bin], re = bbase[bin+1];
  for (int i = rb + t; i < re; i += 1024){
    int2 e = ebuf[i];
    int p = atomicAdd(&cur[e.y - (bin << 8)], 1);
    srcCSR[p] = e.x;
  }
}

// ---------------- degree sort (descending), block-local counting sort ----------------
__global__ __launch_bounds__(1024) void k_dhist_blk(const int* __restrict__ count,
                                                    int* __restrict__ blockhist){
  __shared__ int hist[DB];
  int t = threadIdx.x, b = blockIdx.x;
  if (t < DB) hist[t] = 0;
  __syncthreads();
  int i = b*1024 + t;
  if (i < NN){
    int deg = count[i]; if (deg > DB-1) deg = DB-1;
    atomicAdd(&hist[DB-1-deg], 1);
  }
  __syncthreads();
  if (t < DB) blockhist[t*NB + b] = hist[t];
}

__global__ __launch_bounds__(DB) void k_dcol(const int* __restrict__ blockhist,
                                             int* __restrict__ blockoffs,
                                             int* __restrict__ dbase){
  int k = threadIdx.x;
  int run = 0;
  #pragma unroll 5
  for (int b = 0; b < NB; ++b){
    int v = blockhist[k*NB + b];
    blockoffs[k*NB + b] = run;
    run += v;
  }
  __shared__ int tmp[DB];
  int v = run;
  for (int off = 1; off < DB; off <<= 1){
    tmp[k] = v; __syncthreads();
    int add = (k >= off) ? tmp[k - off] : 0;
    __syncthreads();
    v += add;
  }
  dbase[k] = v - run;
}

__global__ __launch_bounds__(1024) void k_dscatter_blk(const int* __restrict__ count,
                                                       const int* __restrict__ blockoffs,
                                                       const int* __restrict__ dbase,
                                                       int* __restrict__ perm){
  __shared__ int hist[DB];
  int t = threadIdx.x, b = blockIdx.x;
  if (t < DB) hist[t] = 0;
  __syncthreads();
  int i = b*1024 + t;
  if (i < NN){
    int deg = count[i]; if (deg > DB-1) deg = DB-1;
    int bin = DB-1-deg;
    int rank = atomicAdd(&hist[bin], 1);
    int pos = dbase[bin] + blockoffs[bin*NB + b] + rank;
    perm[pos] = i;
  }
}

// ---------------- fp16 helpers ----------------
__device__ __forceinline__ float4 cvt_row(uint2 r){
  __half2 h0, h1;
  memcpy(&h0, &r.x, 4); memcpy(&h1, &r.y, 4);
  float2 f0 = __half22float2(h0), f1 = __half22float2(h1);
  return make_float4(f0.x, f0.y, f1.x, f1.y);
}
__device__ __forceinline__ unsigned pack_h2(float x, float y){
  __half2 h = __floats2half2_rn(x, y);
  unsigned u; memcpy(&u, &h, 4); return u;
}

// ---------------- compute ----------------
__global__ __launch_bounds__(256) void k_prologue(
    const float* __restrict__ x, const float* __restrict__ W0, const float* __restrict__ b0,
    const float* __restrict__ Ws0, const float* __restrict__ al0, const float* __restrict__ ar0,
    __half* __restrict__ hp_out, float* __restrict__ hl_out, float* __restrict__ hr_out){
  __shared__ __align__(16) float w0[128*32];
  __shared__ __align__(16) float w1[32*32];
  int t = threadIdx.x;
  for (int i = t; i < 4096; i += 256) w0[i] = W0[i];
  for (int i = t; i < 1024; i += 256) w1[i] = Ws0[i];
  __syncthreads();
  int g = t >> 5, lane = t & 31;
  int n = blockIdx.x*8 + g;                 // 6250*8 == 50000
  const float4* x4 = (const float4*)(x + (size_t)n*128);
  float h = b0[lane];
  #pragma unroll
  for (int j4 = 0; j4 < 32; ++j4){
    float4 xv = x4[j4];
    h += xv.x * w0[(j4*4+0)*32 + lane];
    h += xv.y * w0[(j4*4+1)*32 + lane];
    h += xv.z * w0[(j4*4+2)*32 + lane];
    h += xv.w * w0[(j4*4+3)*32 + lane];
  }
  float hp = 0.f;
  #pragma unroll
  for (int j = 0; j < 32; ++j) hp += __shfl(h, j, 32) * w1[j*32 + lane];
  float tl = hp*al0[lane], tr = hp*ar0[lane];
  #pragma unroll
  for (int m = 1; m < 32; m <<= 1){ tl += __shfl_xor(tl, m); tr += __shfl_xor(tr, m); }
  hp_out[(size_t)n*32 + lane] = __float2half(hp);
  if (lane == 0){ hl_out[n] = tl; hr_out[n] = tr; }
  if (blockIdx.x == 0){
    if (g == 0) hp_out[(size_t)NN*32 + lane] = __float2half(0.f);  // pad row
    if (t == 0) hl_out[NN] = -1e30f;                               // sentinel -> e=0
  }
}

// One SuperGAT layer. Octet = one dst, 8 dst/wave. Segments padded to x4 with
// PHYSICAL sentinel (src=NN stored in srcCSR) -> idx loads are one int4 per 4
// edges (2.25 VMEM transactions/edge total). Double-buffered pipeline: rows/hl
// at depth 1 group, idx at depth 2 groups. Whole-group select handles
// cross-segment overrun (degree-sorted waves keep waste tiny).
__global__ __launch_bounds__(256) void k_layer(
    const __half* __restrict__ hp, const float* __restrict__ hl, const float* __restrict__ hr,
    const int* __restrict__ offs, const int* __restrict__ srcCSR, const int* __restrict__ perm,
    const float* __restrict__ bcur,
    const float* __restrict__ Wn, const float* __restrict__ aln, const float* __restrict__ arn,
    const float* __restrict__ b16,
    __half* __restrict__ hp_out, float* __restrict__ hl_out, float* __restrict__ hr_out,
    float* __restrict__ final_out, int last){
  __shared__ __align__(16) float wl[1024];
  __shared__ __align__(16) float xb[32*36];
  int t = threadIdx.x;
  int nW = last ? 512 : 1024;
  for (int i = t; i < nW; i += 256) wl[i] = Wn[i];
  __syncthreads();
  int lane = t & 63;
  int li = lane & 7;
  int slot = t >> 3;
  int d = perm[blockIdx.x*32 + slot];
  int beg = offs[d];                    // multiple of 4 -> int4 aligned
  int lenP = offs[d+1] - beg;           // padded length (x4); garbage for d==NN
  int ng = (d < NN) ? (lenP >> 2) : 0;  // own 4-edge groups
  float4 hpd4 = cvt_row(*(const uint2*)(hp + ((size_t)d << 5) + (li << 2)));
  float hrd = hr[d];

  int maxg = ng;
  #pragma unroll
  for (int m = 1; m < 64; m <<= 1) maxg = max(maxg, __shfl_xor(maxg, m));

  auto LD4 = [&](int g)->int4{
    int4 q = *(const int4*)(srcCSR + beg + (g << 2));   // in-bounds via slack
    if (g >= ng){ q.x = NN; q.y = NN; q.z = NN; q.w = NN; }  // overrun -> sentinel
    return q;
  };
  auto ROW = [&](int s)->uint2{
    return *(const uint2*)(hp + ((size_t)s << 5) + (li << 2));
  };
  float4 acc = {0.f,0.f,0.f,0.f};
  float den = 0.f;
  auto EDGE = [&](uint2 r, float g){
    float4 v = cvt_row(r);
    float p = v.x*hpd4.x + v.y*hpd4.y + v.z*hpd4.z + v.w*hpd4.w;
    p += __shfl_xor(p, 1); p += __shfl_xor(p, 2); p += __shfl_xor(p, 4);
    float a = (g + hrd) * (1.f/(1.f + __expf(-p)));
    a = fmaxf(a, 0.2f*a);
    float e = __expf(a);
    den += e;
    acc.x += v.x*e; acc.y += v.y*e; acc.z += v.z*e; acc.w += v.w*e;
  };

  // pipeline preamble: group0 rows+hl, group1 idx
  int4 qA = LD4(0);
  uint2 rA0=ROW(qA.x), rA1=ROW(qA.y), rA2=ROW(qA.z), rA3=ROW(qA.w);
  float gA0=hl[qA.x], gA1=hl[qA.y], gA2=hl[qA.z], gA3=hl[qA.w];
  int4 qB = LD4(1);

  for (int g = 0; g < maxg; g += 2){
    uint2 rB0=ROW(qB.x), rB1=ROW(qB.y), rB2=ROW(qB.z), rB3=ROW(qB.w);
    float gB0=hl[qB.x], gB1=hl[qB.y], gB2=hl[qB.z], gB3=hl[qB.w];
    int4 qN = LD4(g + 2);
    EDGE(rA0,gA0); EDGE(rA1,gA1); EDGE(rA2,gA2); EDGE(rA3,gA3);
    rA0=ROW(qN.x); rA1=ROW(qN.y); rA2=ROW(qN.z); rA3=ROW(qN.w);
    gA0=hl[qN.x]; gA1=hl[qN.y]; gA2=hl[qN.z]; gA3=hl[qN.w];
    qB = LD4(g + 3);
    EDGE(rB0,gB0); EDGE(rB1,gB1); EDGE(rB2,gB2); EDGE(rB3,gB3);
  }

  float rden = 1.f/den;                 // dummy octet: 0/0 NaN, stores guarded
  float4 b4 = *((const float4*)bcur + li);
  float4 h4;
  h4.x = fmaxf(acc.x*rden + b4.x, 0.f);
  h4.y = fmaxf(acc.y*rden + b4.y, 0.f);
  h4.z = fmaxf(acc.z*rden + b4.z, 0.f);
  h4.w = fmaxf(acc.w*rden + b4.w, 0.f);
  float* hrow = xb + slot*36;
  *((float4*)hrow + li) = h4;           // same-wave LDS write->read (lgkmcnt)

  if (!last){
    float4 o = {0.f,0.f,0.f,0.f};
    #pragma unroll
    for (int q = 0; q < 8; ++q){
      float4 hq = *((const float4*)hrow + q);
      float4 w0 = *(const float4*)(wl + (4*q+0)*32 + 4*li);
      float4 w1 = *(const float4*)(wl + (4*q+1)*32 + 4*li);
      float4 w2 = *(const float4*)(wl + (4*q+2)*32 + 4*li);
      float4 w3 = *(const float4*)(wl + (4*q+3)*32 + 4*li);
      o.x += hq.x*w0.x + hq.y*w1.x + hq.z*w2.x + hq.w*w3.x;
      o.y += hq.x*w0.y + hq.y*w1.y + hq.z*w2.y + hq.w*w3.y;
      o.z += hq.x*w0.z + hq.y*w1.z + hq.z*w2.z + hq.w*w3.z;
      o.w += hq.x*w0.w + hq.y*w1.w + hq.z*w2.w + hq.w*w3.w;
    }
    float4 a4 = *((const float4*)aln + li);
    float4 r4 = *((const float4*)arn + li);
    float tl = o.x*a4.x + o.y*a4.y + o.z*a4.z + o.w*a4.w;
    float tr = o.x*r4.x + o.y*r4.y + o.z*r4.z + o.w*r4.w;
    tl += __shfl_xor(tl, 1); tl += __shfl_xor(tl, 2); tl += __shfl_xor(tl, 4);
    tr += __shfl_xor(tr, 1); tr += __shfl_xor(tr, 2); tr += __shfl_xor(tr, 4);
    if (d < NN){
      uint2 st; st.x = pack_h2(o.x, o.y); st.y = pack_h2(o.z, o.w);
      *(uint2*)(hp_out + ((size_t)d << 5) + (li << 2)) = st;
      if (li == 0){ hl_out[d] = tl; hr_out[d] = tr; }
    }
    if (blockIdx.x == 0){
      if (t < 32) hp_out[(size_t)NN*32 + t] = __float2half(0.f);
      if (t == 0) hl_out[NN] = -1e30f;
    }
  } else {
    const float2* b2p = (const float2*)b16;
    float2 o = b2p[li];
    #pragma unroll
    for (int q = 0; q < 8; ++q){
      float4 hq = *((const float4*)hrow + q);
      float2 w0 = *(const float2*)(wl + (4*q+0)*16 + 2*li);
      float2 w1 = *(const float2*)(wl + (4*q+1)*16 + 2*li);
      float2 w2 = *(const float2*)(wl + (4*q+2)*16 + 2*li);
      float2 w3 = *(const float2*)(wl + (4*q+3)*16 + 2*li);
      o.x += hq.x*w0.x + hq.y*w1.x + hq.z*w2.x + hq.w*w3.x;
      o.y += hq.x*w0.y + hq.y*w1.y + hq.z*w2.y + hq.w*w3.y;
    }
    if (d < NN) *((float2*)(final_out + (size_t)d*16) + li) = o;
  }
}

extern "C" void kernel_launch(void* const* d_in, const int* in_sizes, int n_in,
                              void* d_out, int out_size, void* d_ws, size_t ws_size,
                              hipStream_t stream){
  const float* x   = (const float*)d_in[0];
  const int*   ei  = (const int*)  d_in[1];
  const float* W0  = (const float*)d_in[2];
  const float* b0  = (const float*)d_in[3];
  const float* Ws  = (const float*)d_in[4];
  const float* al  = (const float*)d_in[5];
  const float* ar  = (const float*)d_in[6];
  const float* bs  = (const float*)d_in[7];
  const float* W16 = (const float*)d_in[8];
  const float* b16 = (const float*)d_in[9];
  float* out = (float*)d_out;

  char* w = (char*)d_ws;
  int* count     = (int*)w;   w += 50176*sizeof(int);
  int* offs      = (int*)w;   w += 50432*sizeof(int);
  int* srcCSR    = (int*)w;   w += (size_t)PADCAP*sizeof(int);
  int* bsums     = (int*)w;   w += 256*sizeof(int);
  int* boffs     = (int*)w;   w += 256*sizeof(int);
  int* perm      = (int*)w;   w += 50176*sizeof(int);
  int* blockhist = (int*)w;   w += DB*NB*sizeof(int);
  int* blockoffs = (int*)w;   w += DB*NB*sizeof(int);
  int* dbase     = (int*)w;   w += DB*sizeof(int);
  int* ebh       = (int*)w;   w += (size_t)EBINS*NBK*sizeof(int) + 16;
  int* ebhoff    = (int*)w;   w += (size_t)EBINS*NBK*sizeof(int) + 16;
  int* btot      = (int*)w;   w += 256*sizeof(int);
  int* bbase     = (int*)w;   w += 256*sizeof(int);
  int2* ebuf     = (int2*)w;  w += (size_t)(NBK*1024)*sizeof(int2);
  __half* hpA  = (__half*)w; w += (size_t)(NN+16)*32*sizeof(__half);
  __half* hpB  = (__half*)w; w += (size_t)(NN+16)*32*sizeof(__half);
  float* hlA   = (float*)w; w += 50176*sizeof(float);
  float* hrA   = (float*)w; w += 50176*sizeof(float);
  float* hlB   = (float*)w; w += 50176*sizeof(float);
  float* hrB   = (float*)w; w += 50176*sizeof(float);
  // ~20.2 MB of d_ws

  // CSR build: bin -> scan -> scatter (no global atomics, dense writes)
  k_fill    <<<PADCAP/256, 256, 0, stream>>>(srcCSR);
  k_permfill<<<196, 256, 0, stream>>>(perm);
  k_ebhist  <<<NBK, 1024, 0, stream>>>(ei, ebh);
  k_escan1  <<<EBINS, 1024, 0, stream>>>(ebh, ebhoff, btot);
  k_escan2  <<<1, 256, 0, stream>>>(btot, bbase);
  k_ebin    <<<NBK, 1024, 0, stream>>>(ei, ebhoff, bbase, ebuf);
  k_ecnt    <<<EBINS, 1024, 0, stream>>>(ebuf, bbase, count);
  k_bsum    <<<196, 256, 0, stream>>>(count, bsums);
  k_bscan   <<<1, 256, 0, stream>>>(bsums, boffs, 196);
  k_scan    <<<196, 256, 0, stream>>>(count, boffs, offs);
  k_escatter<<<EBINS, 1024, 0, stream>>>(ebuf, bbase, offs, srcCSR);
  // degree sort (descending)
  k_dhist_blk   <<<NB, 1024, 0, stream>>>(count, blockhist);
  k_dcol        <<<1,  DB,   0, stream>>>(blockhist, blockoffs, dbase);
  k_dscatter_blk<<<NB, 1024, 0, stream>>>(count, blockoffs, dbase, perm);

  // h0 = x@W0+b0 fused with layer-0 transform
  k_prologue<<<6250, 256, 0, stream>>>(x, W0, b0, Ws, al, ar, hpA, hlA, hrA);

  int nblk = (NN + 31) / 32 + 1;   // 1563 blocks x 32 dst = 50016 slots
  for (int l = 0; l < 15; ++l){
    const __half* hin = (l & 1) ? hpB : hpA;
    const float* hlin = (l & 1) ? hlB : hlA;
    const float* hrin = (l & 1) ? hrB : hrA;
    __half* hout = (l & 1) ? hpA : hpB;
    float* hlout = (l & 1) ? hlA : hlB;
    float* hrout = (l & 1) ? hrA : hrB;
    int last = (l == 14);
    const float* Wn  = last ? W16 : (Ws + (size_t)(l+1)*1024);
    const float* aln = last ? al  : (al + (size_t)(l+1)*32);
    const float* arn = last ? ar  : (ar + (size_t)(l+1)*32);
    k_layer<<<nblk, 256, 0, stream>>>(hin, hlin, hrin, offs, srcCSR, perm,
                                      bs + (size_t)l*32,
                                      Wn, aln, arn, b16,
                                      hout, hlout, hrout, out, last);
  }
}